// Round 1
// baseline (612.325 us; speedup 1.0000x reference)
//
#include <hip/hip_runtime.h>
#include <stdint.h>

#define B_Q     4096
#define N_SLOTS 32768
#define KD      128

#define BM 64
#define BN 64
#define NSPLIT 8
#define NCHUNK (N_SLOTS / NSPLIT)   // 4096
#define NTILES (NCHUNK / BN)        // 64

// ---------------- k inverse-norm kernel: one wave per row ----------------
__global__ void knorm_kernel(const float* __restrict__ k, float* __restrict__ invk) {
    int gid  = blockIdx.x * blockDim.x + threadIdx.x;
    int row  = gid >> 6;            // wave id
    int lane = threadIdx.x & 63;
    if (row >= N_SLOTS) return;
    float2 v = reinterpret_cast<const float2*>(k + (size_t)row * KD)[lane];
    float s = v.x * v.x + v.y * v.y;
    #pragma unroll
    for (int off = 32; off; off >>= 1) s += __shfl_xor(s, off);
    if (lane == 0) invk[row] = 1.0f / fmaxf(sqrtf(s), 1e-12f);
}

__device__ inline unsigned long long shfl_xor_u64(unsigned long long v, int mask, int width) {
    unsigned int lo = (unsigned int)v, hi = (unsigned int)(v >> 32);
    lo = __shfl_xor(lo, mask, width);
    hi = __shfl_xor(hi, mask, width);
    return ((unsigned long long)hi << 32) | lo;
}

// ordered-float encoding: monotone map f32 -> u32
__device__ inline unsigned int ord_f32(float f) {
    unsigned int u = __float_as_uint(f);
    return (u & 0x80000000u) ? ~u : (u | 0x80000000u);
}

// ---------------- fused GEMM + argmax ----------------
// grid: (B_Q/BM, NSPLIT); block: 256
__global__ __launch_bounds__(256, 2) void sim_argmax_kernel(
    const float* __restrict__ Q, const float* __restrict__ Kb,
    const float* __restrict__ invk, unsigned long long* __restrict__ best)
{
    // [row][chunk] of float4; chunk index XOR-swizzled by ((row>>2)&7)
    __shared__ float4 As[BM][32];
    __shared__ float4 Bs[BN][32];

    const int tid = threadIdx.x;
    const int q0  = blockIdx.x * BM;
    const int n0  = blockIdx.y * NCHUNK;

    // stage A (Q tile) once: 64 rows x 32 float4 chunks = 2048
    {
        const float4* Qg = reinterpret_cast<const float4*>(Q + (size_t)q0 * KD);
        #pragma unroll
        for (int i = 0; i < 8; ++i) {
            int f = i * 256 + tid;
            int r = f >> 5, c = f & 31;
            As[r][c ^ ((r >> 2) & 7)] = Qg[f];
        }
    }

    const int tr = tid >> 4;        // 0..15 -> rows tr*4..tr*4+3
    const int tc = tid & 15;        // 0..15 -> cols tc*4..tc*4+3
    const int r0 = tr * 4;

    unsigned long long pbest[4] = {0ull, 0ull, 0ull, 0ull};

    for (int t = 0; t < NTILES; ++t) {
        const int nb = n0 + t * BN;
        __syncthreads();            // protect Bs (and As on t==0) writes vs reads
        {
            const float4* Kg = reinterpret_cast<const float4*>(Kb + (size_t)nb * KD);
            #pragma unroll
            for (int i = 0; i < 8; ++i) {
                int f = i * 256 + tid;
                int r = f >> 5, c = f & 31;
                Bs[r][c ^ ((r >> 2) & 7)] = Kg[f];
            }
        }
        __syncthreads();

        float acc[4][4] = {};
        for (int kc = 0; kc < 32; ++kc) {
            const int sa = kc ^ (tr & 7);
            const int sb = kc ^ (tc & 7);
            float4 a[4], b[4];
            #pragma unroll
            for (int i = 0; i < 4; ++i) a[i] = As[r0 + i][sa];
            #pragma unroll
            for (int j = 0; j < 4; ++j) b[j] = Bs[tc * 4 + j][sb];
            #pragma unroll
            for (int i = 0; i < 4; ++i)
                #pragma unroll
                for (int j = 0; j < 4; ++j)
                    acc[i][j] += a[i].x * b[j].x + a[i].y * b[j].y
                               + a[i].z * b[j].z + a[i].w * b[j].w;
        }

        // epilogue: scale by 1/||k_n||, fold into packed running argmax
        #pragma unroll
        for (int j = 0; j < 4; ++j) {
            int n = nb + tc * 4 + j;
            float iv = invk[n];
            #pragma unroll
            for (int i = 0; i < 4; ++i) {
                float v = acc[i][j] * iv;
                unsigned long long p =
                    ((unsigned long long)ord_f32(v) << 32) | (unsigned int)(~n);
                if (p > pbest[i]) pbest[i] = p;
            }
        }
    }

    // reduce across the 16 lanes (same tr) sharing each row group
    #pragma unroll
    for (int i = 0; i < 4; ++i) {
        unsigned long long p = pbest[i];
        #pragma unroll
        for (int off = 8; off; off >>= 1) {
            unsigned long long o = shfl_xor_u64(p, off, 16);
            if (o > p) p = o;
        }
        if (tc == 0) atomicMax(&best[q0 + r0 + i], p);
    }
}

// ---------------- decode packed best -> int32 index ----------------
__global__ void decode_kernel(const unsigned long long* __restrict__ best,
                              int* __restrict__ out) {
    int i = blockIdx.x * blockDim.x + threadIdx.x;
    if (i < B_Q) out[i] = (int)(~(unsigned int)(best[i] & 0xFFFFFFFFull));
}

extern "C" void kernel_launch(void* const* d_in, const int* in_sizes, int n_in,
                              void* d_out, int out_size, void* d_ws, size_t ws_size,
                              hipStream_t stream) {
    const float* Q  = (const float*)d_in[0];   // 4096 x 128
    const float* Kb = (const float*)d_in[1];   // 32768 x 128
    float* invk = (float*)d_ws;                                   // 128 KB
    unsigned long long* best =
        (unsigned long long*)((char*)d_ws + (size_t)N_SLOTS * 4); // 32 KB
    int* out = (int*)d_out;

    hipMemsetAsync(best, 0, (size_t)B_Q * sizeof(unsigned long long), stream);
    knorm_kernel<<<N_SLOTS / 4, 256, 0, stream>>>(Kb, invk);
    dim3 grid(B_Q / BM, NSPLIT);
    sim_argmax_kernel<<<grid, 256, 0, stream>>>(Q, Kb, invk, best);
    decode_kernel<<<B_Q / 256, 256, 0, stream>>>(best, out);
}

// Round 2
// 600.645 us; speedup vs baseline: 1.0194x; 1.0194x over previous
//
#include <hip/hip_runtime.h>
#include <stdint.h>

#define B_Q     4096
#define N_SLOTS 32768
#define KD      128

#define BM 128
#define BN 128
#define NSPLIT 32
#define NCHUNK (N_SLOTS / NSPLIT)     // 1024 cols per block
#define NT_BLK (NCHUNK / BN)          // 8 n-tiles per block

// ---------------- k inverse-norm kernel: one wave per row ----------------
__global__ void knorm_kernel(const float* __restrict__ k, float* __restrict__ invk) {
    int gid  = blockIdx.x * blockDim.x + threadIdx.x;
    int row  = gid >> 6;
    int lane = threadIdx.x & 63;
    if (row >= N_SLOTS) return;
    float2 v = reinterpret_cast<const float2*>(k + (size_t)row * KD)[lane];
    float s = v.x * v.x + v.y * v.y;
    #pragma unroll
    for (int off = 32; off; off >>= 1) s += __shfl_xor(s, off);
    if (lane == 0) invk[row] = 1.0f / fmaxf(sqrtf(s), 1e-12f);
}

__device__ inline unsigned long long shfl_xor_u64_w16(unsigned long long v, int mask) {
    unsigned int lo = (unsigned int)v, hi = (unsigned int)(v >> 32);
    lo = __shfl_xor(lo, mask, 16);
    hi = __shfl_xor(hi, mask, 16);
    return ((unsigned long long)hi << 32) | lo;
}

// ordered-float encoding: monotone map f32 -> u32
__device__ inline unsigned int ord_f32(float f) {
    unsigned int u = __float_as_uint(f);
    return (u & 0x80000000u) ? ~u : (u | 0x80000000u);
}

// ---------------- fused GEMM + argmax, 8x8 micro-tile ----------------
// grid: (B_Q/BM, NSPLIT); block: 256 (16x16)
__global__ __launch_bounds__(256, 2) void sim_argmax_kernel(
    const float* __restrict__ Q, const float* __restrict__ Kb,
    const float* __restrict__ invk, unsigned long long* __restrict__ best)
{
    // [row][chunk] of float4, 16 chunks (BK=64); chunk XOR-swizzled by (row&15)
    __shared__ float4 As[BM][16];   // 32 KB
    __shared__ float4 Bs[BN][16];   // 32 KB

    const int tid = threadIdx.x;
    const int ty  = tid >> 4;       // 0..15: owns rows ty+16i
    const int tx  = tid & 15;       // 0..15: owns cols tx+16j
    const int q0  = blockIdx.x * BM;
    const int n0  = blockIdx.y * NCHUNK;
    const int cs  = tx ^ ty;        // swizzled staging column (constant per thread)

    const float4* Qg = reinterpret_cast<const float4*>(Q);
    const float4* Kg = reinterpret_cast<const float4*>(Kb);

    unsigned long long pbest[8];
    #pragma unroll
    for (int i = 0; i < 8; ++i) pbest[i] = 0ull;

    float4 pa[8], pb[8];
    // prefetch stage s=0 (t=0, kk=0)
    #pragma unroll
    for (int i = 0; i < 8; ++i) {
        pa[i] = Qg[(q0 + 16 * i + ty) * 32 + tx];
        pb[i] = Kg[(n0 + 16 * i + ty) * 32 + tx];
    }

    float acc[8][8];

    // 16 stages: s = t*2 + kk  (t: n-tile 0..7, kk: k-half 0..1)
    #pragma unroll 1
    for (int s = 0; s < 2 * NT_BLK; ++s) {
        const int kk   = s & 1;
        const int tcol = s >> 1;

        __syncthreads();            // previous compute done reading LDS
        #pragma unroll
        for (int i = 0; i < 8; ++i) {
            As[16 * i + ty][cs] = pa[i];
            Bs[16 * i + ty][cs] = pb[i];
        }
        __syncthreads();

        if (s < 2 * NT_BLK - 1) {   // prefetch next stage (overlaps compute)
            const int kk2 = (s + 1) & 1;
            const int nc2 = n0 + ((s + 1) >> 1) * BN;
            #pragma unroll
            for (int i = 0; i < 8; ++i) {
                pa[i] = Qg[(q0 + 16 * i + ty) * 32 + kk2 * 16 + tx];
                pb[i] = Kg[(nc2 + 16 * i + ty) * 32 + kk2 * 16 + tx];
            }
        }

        if (kk == 0) {
            #pragma unroll
            for (int i = 0; i < 8; ++i)
                #pragma unroll
                for (int j = 0; j < 8; ++j) acc[i][j] = 0.0f;
        }

        #pragma unroll 2
        for (int kc = 0; kc < 16; ++kc) {
            float4 a[8], b[8];
            const int ca = kc ^ ty;
            const int cb = kc ^ tx;
            #pragma unroll
            for (int i = 0; i < 8; ++i) a[i] = As[16 * i + ty][ca];
            #pragma unroll
            for (int j = 0; j < 8; ++j) b[j] = Bs[16 * j + tx][cb];
            #pragma unroll
            for (int i = 0; i < 8; ++i)
                #pragma unroll
                for (int j = 0; j < 8; ++j) {
                    acc[i][j] = fmaf(a[i].x, b[j].x, acc[i][j]);
                    acc[i][j] = fmaf(a[i].y, b[j].y, acc[i][j]);
                    acc[i][j] = fmaf(a[i].z, b[j].z, acc[i][j]);
                    acc[i][j] = fmaf(a[i].w, b[j].w, acc[i][j]);
                }
        }

        if (kk == 1) {              // epilogue for n-tile tcol
            const int nc = n0 + tcol * BN;
            #pragma unroll
            for (int j = 0; j < 8; ++j) {
                const int n = nc + 16 * j + tx;
                const float iv = invk[n];
                #pragma unroll
                for (int i = 0; i < 8; ++i) {
                    float v = acc[i][j] * iv;
                    unsigned long long p =
                        ((unsigned long long)ord_f32(v) << 32) | (unsigned int)(~n);
                    if (p > pbest[i]) pbest[i] = p;
                }
            }
        }
    }

    // reduce across the 16 tx lanes sharing each row (same wave: lane = (ty&3)*16+tx)
    #pragma unroll
    for (int i = 0; i < 8; ++i) {
        unsigned long long p = pbest[i];
        #pragma unroll
        for (int off = 8; off; off >>= 1) {
            unsigned long long o = shfl_xor_u64_w16(p, off);
            if (o > p) p = o;
        }
        if (tx == 0) atomicMax(&best[q0 + 16 * i + ty], p);
    }
}

// ---------------- decode packed best -> int32 index ----------------
__global__ void decode_kernel(const unsigned long long* __restrict__ best,
                              int* __restrict__ out) {
    int i = blockIdx.x * blockDim.x + threadIdx.x;
    if (i < B_Q) out[i] = (int)(~(unsigned int)(best[i] & 0xFFFFFFFFull));
}

extern "C" void kernel_launch(void* const* d_in, const int* in_sizes, int n_in,
                              void* d_out, int out_size, void* d_ws, size_t ws_size,
                              hipStream_t stream) {
    const float* Q  = (const float*)d_in[0];   // 4096 x 128
    const float* Kb = (const float*)d_in[1];   // 32768 x 128
    float* invk = (float*)d_ws;                                   // 128 KB
    unsigned long long* best =
        (unsigned long long*)((char*)d_ws + (size_t)N_SLOTS * 4); // 32 KB
    int* out = (int*)d_out;

    hipMemsetAsync(best, 0, (size_t)B_Q * sizeof(unsigned long long), stream);
    knorm_kernel<<<N_SLOTS / 4, 256, 0, stream>>>(Kb, invk);
    dim3 grid(B_Q / BM, NSPLIT);
    sim_argmax_kernel<<<grid, 256, 0, stream>>>(Q, Kb, invk, best);
    decode_kernel<<<B_Q / 256, 256, 0, stream>>>(best, out);
}

// Round 3
// 165.452 us; speedup vs baseline: 3.7009x; 3.6303x over previous
//
#include <hip/hip_runtime.h>
#include <stdint.h>

#define B_Q     4096
#define N_SLOTS 32768
#define KD      128
#define BM      128
#define BN      128
#define BK      64

typedef __bf16 bf16x8 __attribute__((ext_vector_type(8)));
typedef float  f32x4  __attribute__((ext_vector_type(4)));

// ---- bf16 helpers (RNE) ----
__device__ __forceinline__ unsigned short f2bf(float f) {
    unsigned u = __float_as_uint(f);
    unsigned r = u + 0x7FFFu + ((u >> 16) & 1u);
    return (unsigned short)(r >> 16);
}
__device__ __forceinline__ float bf2f(unsigned short b) {
    return __uint_as_float(((unsigned)b) << 16);
}

// ordered-float: monotone f32 -> u32
__device__ __forceinline__ unsigned int ord_f32(float f) {
    unsigned int u = __float_as_uint(f);
    return (u & 0x80000000u) ? ~u : (u | 0x80000000u);
}

__device__ __forceinline__ unsigned long long shfl_xor_u64_w16(unsigned long long v, int mask) {
    unsigned int lo = (unsigned int)v, hi = (unsigned int)(v >> 32);
    lo = __shfl_xor(lo, mask, 16);
    hi = __shfl_xor(hi, mask, 16);
    return ((unsigned long long)hi << 32) | lo;
}

__device__ __forceinline__ void gload_lds16(const void* g, void* l) {
    __builtin_amdgcn_global_load_lds(
        (const __attribute__((address_space(1))) unsigned int*)g,
        (__attribute__((address_space(3))) unsigned int*)l, 16, 0, 0);
}

// ---------------- prep: K -> normalized bf16 hi/lo; Q -> bf16 hi/lo ----------------
// one wave per row; rows [0,N_SLOTS) = K, [N_SLOTS, N_SLOTS+B_Q) = Q
__global__ void prep_kernel(const float* __restrict__ Q, const float* __restrict__ Kb,
                            unsigned short* __restrict__ qhi, unsigned short* __restrict__ qlo,
                            unsigned short* __restrict__ khi, unsigned short* __restrict__ klo) {
    const int wid  = blockIdx.x * 4 + (threadIdx.x >> 6);
    const int lane = threadIdx.x & 63;
    const bool isK = wid < N_SLOTS;
    const int row  = isK ? wid : wid - N_SLOTS;
    const float* src = isK ? Kb : Q;
    float2 v = reinterpret_cast<const float2*>(src + (size_t)row * KD)[lane];
    float scale = 1.0f;
    if (isK) {
        float ss = v.x * v.x + v.y * v.y;
        #pragma unroll
        for (int off = 32; off; off >>= 1) ss += __shfl_xor(ss, off);
        scale = 1.0f / fmaxf(sqrtf(ss), 1e-12f);
    }
    float x = v.x * scale, y = v.y * scale;
    unsigned short hx = f2bf(x), hy = f2bf(y);
    unsigned short lx = f2bf(x - bf2f(hx)), ly = f2bf(y - bf2f(hy));
    unsigned short* dh = isK ? khi : qhi;
    unsigned short* dl = isK ? klo : qlo;
    ((unsigned int*)(dh + (size_t)row * KD))[lane] = (unsigned int)hx | ((unsigned int)hy << 16);
    ((unsigned int*)(dl + (size_t)row * KD))[lane] = (unsigned int)lx | ((unsigned int)ly << 16);
}

// ---------------- fused split-bf16 MFMA GEMM + argmax ----------------
// grid (B_Q/BM, N_SLOTS/BN), block 256 = 4 waves (2x2 quadrants of 64x64).
// LDS tiles [128 rows][64 cols] bf16, row pitch 128 B; 16B slot s of row r holds
// logical k-chunk (s ^ (r&7)) -> frag ds_read_b128 is 2-way bank aliased = free.
// Staged by global_load_lds (linear LDS dest) with inverse-swizzled global source.
__global__ __launch_bounds__(256, 2) void mfma_argmax_kernel(
    const unsigned short* __restrict__ qhi, const unsigned short* __restrict__ qlo,
    const unsigned short* __restrict__ khi, const unsigned short* __restrict__ klo,
    unsigned long long* __restrict__ best)
{
    __shared__ unsigned char lds[65536];   // 4 tiles x 16 KB: qh, ql, kh, kl

    const int tid  = threadIdx.x;
    const int lane = tid & 63;
    const int w    = tid >> 6;
    const int wr   = w >> 1;               // quadrant row 0..1
    const int wc   = w & 1;                // quadrant col 0..1
    const int q0   = blockIdx.x * BM;
    const int n0   = blockIdx.y * BN;
    const int l15  = lane & 15;
    const int lg   = lane >> 4;            // k-group 0..3

    f32x4 acc[4][4];
    #pragma unroll
    for (int i = 0; i < 4; ++i)
        #pragma unroll
        for (int j = 0; j < 4; ++j) {
            acc[i][j][0] = 0.f; acc[i][j][1] = 0.f;
            acc[i][j][2] = 0.f; acc[i][j][3] = 0.f;
        }

    for (int ks = 0; ks < 2; ++ks) {
        if (ks) __syncthreads();           // all reads of previous tiles done
        // stage 4 tiles; wave w stages 1KB chunks 4w..4w+3 of each tile
        #pragma unroll
        for (int t = 0; t < 4; ++t) {
            const unsigned short* gb = (t == 0) ? qhi : (t == 1) ? qlo : (t == 2) ? khi : klo;
            const int rbase = (t < 2) ? q0 : n0;
            #pragma unroll
            for (int i = 0; i < 4; ++i) {
                const int ch   = w * 4 + i;
                const int row  = ch * 8 + (lane >> 3);     // 8 rows per 1KB chunk
                const int slot = lane & 7;                 // 16B slot within row
                const int gc   = slot ^ (row & 7);         // inverse swizzle on source
                const void* g = (const void*)(gb + (size_t)(rbase + row) * KD + ks * BK + gc * 8);
                gload_lds16(g, &lds[t * 16384 + ch * 1024]);
            }
        }
        __syncthreads();                   // vmcnt(0) drained by compiler before barrier

        #pragma unroll
        for (int c = 0; c < 2; ++c) {      // two K=32 chunks per k-step
            bf16x8 ah[4], al[4], bh[4], bl[4];
            #pragma unroll
            for (int i = 0; i < 4; ++i) {
                const int ra = wr * 64 + i * 16 + l15;
                const int ca = ((c * 4 + lg) ^ (ra & 7)) * 16;
                ah[i] = *(const bf16x8*)&lds[0 * 16384 + ra * 128 + ca];
                al[i] = *(const bf16x8*)&lds[1 * 16384 + ra * 128 + ca];
                const int rb = wc * 64 + i * 16 + l15;
                const int cb = ((c * 4 + lg) ^ (rb & 7)) * 16;
                bh[i] = *(const bf16x8*)&lds[2 * 16384 + rb * 128 + cb];
                bl[i] = *(const bf16x8*)&lds[3 * 16384 + rb * 128 + cb];
            }
            #pragma unroll
            for (int i = 0; i < 4; ++i)
                #pragma unroll
                for (int j = 0; j < 4; ++j) {
                    acc[i][j] = __builtin_amdgcn_mfma_f32_16x16x32_bf16(ah[i], bh[j], acc[i][j], 0, 0, 0);
                    acc[i][j] = __builtin_amdgcn_mfma_f32_16x16x32_bf16(ah[i], bl[j], acc[i][j], 0, 0, 0);
                    acc[i][j] = __builtin_amdgcn_mfma_f32_16x16x32_bf16(al[i], bh[j], acc[i][j], 0, 0, 0);
                }
        }
    }

    // epilogue: C/D layout col = lane&15, row = (lane>>4)*4 + reg  [m89-verified]
    unsigned long long pb[16];
    #pragma unroll
    for (int i = 0; i < 4; ++i)
        #pragma unroll
        for (int r = 0; r < 4; ++r) {
            unsigned long long p = 0ull;
            #pragma unroll
            for (int j = 0; j < 4; ++j) {
                const int n = n0 + wc * 64 + j * 16 + l15;
                const float v = acc[i][j][r];
                const unsigned long long pk =
                    ((unsigned long long)ord_f32(v) << 32) | (unsigned int)(~n);
                if (pk > p) p = pk;
            }
            pb[i * 4 + r] = p;
        }
    #pragma unroll
    for (int e = 0; e < 16; ++e) {
        unsigned long long p = pb[e];
        #pragma unroll
        for (int m = 8; m; m >>= 1) {
            const unsigned long long o = shfl_xor_u64_w16(p, m);
            if (o > p) p = o;
        }
        if (l15 == 0)
            atomicMax(&best[q0 + wr * 64 + (e >> 2) * 16 + lg * 4 + (e & 3)], p);
    }
}

// ---------------- decode packed best -> int32 index ----------------
__global__ void decode_kernel(const unsigned long long* __restrict__ best,
                              int* __restrict__ out) {
    int i = blockIdx.x * blockDim.x + threadIdx.x;
    if (i < B_Q) out[i] = (int)(~(unsigned int)(best[i] & 0xFFFFFFFFull));
}

// ---------------- fallback (only if ws too small): slow but correct ----------------
__global__ void fallback_kernel(const float* __restrict__ Q, const float* __restrict__ Kb,
                                int* __restrict__ out) {
    __shared__ float q[KD];
    __shared__ unsigned long long red[256];
    const int b = blockIdx.x;
    for (int i = threadIdx.x; i < KD; i += 256) q[i] = Q[(size_t)b * KD + i];
    __syncthreads();
    unsigned long long pbest = 0ull;
    for (int n = threadIdx.x; n < N_SLOTS; n += 256) {
        const float* kr = Kb + (size_t)n * KD;
        float dot = 0.f, ss = 0.f;
        for (int d = 0; d < KD; ++d) { float kv = kr[d]; dot = fmaf(q[d], kv, dot); ss = fmaf(kv, kv, ss); }
        float v = dot / fmaxf(sqrtf(ss), 1e-12f);
        unsigned long long p = ((unsigned long long)ord_f32(v) << 32) | (unsigned int)(~n);
        if (p > pbest) pbest = p;
    }
    red[threadIdx.x] = pbest; __syncthreads();
    for (int s = 128; s; s >>= 1) {
        if (threadIdx.x < (unsigned)s && red[threadIdx.x + s] > red[threadIdx.x])
            red[threadIdx.x] = red[threadIdx.x + s];
        __syncthreads();
    }
    if (threadIdx.x == 0) out[b] = (int)(~(unsigned int)(red[0] & 0xFFFFFFFFull));
}

extern "C" void kernel_launch(void* const* d_in, const int* in_sizes, int n_in,
                              void* d_out, int out_size, void* d_ws, size_t ws_size,
                              hipStream_t stream) {
    const float* Q  = (const float*)d_in[0];   // 4096 x 128
    const float* Kb = (const float*)d_in[1];   // 32768 x 128
    int* out = (int*)d_out;

    const size_t EQ = (size_t)B_Q * KD;        // elements per Q plane
    const size_t EK = (size_t)N_SLOTS * KD;    // elements per K plane
    const size_t NEED = (2 * EQ + 2 * EK) * 2 + (size_t)B_Q * 8;  // ~18.9 MB

    if (ws_size < NEED) {                      // safety net: ws too small
        fallback_kernel<<<B_Q, 256, 0, stream>>>(Q, Kb, out);
        return;
    }

    unsigned short* qhi = (unsigned short*)d_ws;
    unsigned short* qlo = qhi + EQ;
    unsigned short* khi = qlo + EQ;
    unsigned short* klo = khi + EK;
    unsigned long long* best = (unsigned long long*)(klo + EK);

    hipMemsetAsync(best, 0, (size_t)B_Q * 8, stream);
    prep_kernel<<<(N_SLOTS + B_Q) / 4, 256, 0, stream>>>(Q, Kb, qhi, qlo, khi, klo);
    mfma_argmax_kernel<<<dim3(B_Q / BM, N_SLOTS / BN), 256, 0, stream>>>(qhi, qlo, khi, klo, best);
    decode_kernel<<<B_Q / 256, 256, 0, stream>>>(best, out);
}